// Round 5
// baseline (1641.736 us; speedup 1.0000x reference)
//
#include <hip/hip_runtime.h>

// R5 = R3 structure (1 wave per 16 batch, zero LDS/barriers) + poly-tanh.
// GEMMs D[out][batch] = W^T(A) x act^T(B); batch pinned to lane&15; interlayer
// transpose via ds_bpermute. tanh replaced by division/transcendental-free
// odd deg-13 Chebyshev poly on [-3,3] (clamped), full-rate FMAs only —
// removes ~128 exp+rcp quarter-rate trans-pipe ops per step per wave.

typedef _Float16 h2_t __attribute__((ext_vector_type(2)));
typedef _Float16 h8_t __attribute__((ext_vector_type(8)));
typedef __fp16  pk2_t __attribute__((ext_vector_type(2)));
typedef float f4_t __attribute__((ext_vector_type(4)));

union H8 { h8_t v; h2_t h[4]; int i[4]; };
union H2I { h2_t h; pk2_t p; int i; float _f; };

#define DEVI __device__ __forceinline__

DEVI float rcp_f(float x) { return __builtin_amdgcn_rcpf(x); }
DEVI int pkrtz_i(float a, float b) { H2I u; u.p = __builtin_amdgcn_cvt_pkrtz(a, b); return u.i; }
DEVI h2_t pkrtz(float a, float b)  { H2I u; u.p = __builtin_amdgcn_cvt_pkrtz(a, b); return u.h; }
DEVI int bperm(int addr, int src) { return __builtin_amdgcn_ds_bpermute(addr, src); }
DEVI int h2i(h2_t h) { H2I u; u.h = h; return u.i; }

DEVI f4_t mfma16(h8_t a, h8_t b, f4_t c) {
    return __builtin_amdgcn_mfma_f32_16x16x32_f16(a, b, c, 0, 0, 0);
}

// odd deg-13 Chebyshev fit of tanh(x)/x in t=x^2 on |x|<=3, clamped.
// max err ~5e-4 interior, ~1e-2 at deep saturation (clamp) — in budget.
DEVI f4_t tanh4(f4_t x) {
    const float C0 = 0.998522f,   C1 = -0.316821f, C2 = 0.098602f,
                C3 = -0.021366f,  C4 = 2.8242e-3f, C5 = -2.0132e-4f,
                C6 = 5.8923e-6f;
    f4_t r;
#pragma unroll
    for (int i = 0; i < 4; ++i) {
        float xc = fminf(fmaxf(x[i], -3.0f), 3.0f);
        float t = xc * xc;
        float p = fmaf(t, C6, C5);
        p = fmaf(t, p, C4);
        p = fmaf(t, p, C3);
        p = fmaf(t, p, C2);
        p = fmaf(t, p, C1);
        p = fmaf(t, p, C0);
        r[i] = xc * p;
    }
    return r;
}

// 4-way select by quad index q
DEVI int qsel(int q, int a, int b, int c, int d) {
    int x = (q == 0) ? a : b;
    int y = (q == 2) ? c : d;
    return (q < 2) ? x : y;
}

// grey-box CSTR+flash RHS, scaled coords, per-lane (batch = lane&15)
DEVI void fg_eval(const float x[8], float F, float D, float kfg[8]) {
    float Hr  = fmaf(x[0], 0.3f, 0.7f);
    float CAr = fmaf(x[1], 0.2f, 0.5f);
    float CBr = fmaf(x[2], 0.2f, 0.5f);
    float Tr  = fmaf(x[3], 5.0f, 310.0f);
    float Hb  = fmaf(x[4], 0.3f, 0.7f);
    float CAb = fmaf(x[5], 0.2f, 0.5f);
    float CBb = fmaf(x[6], 0.2f, 0.5f);
    float Tb  = fmaf(x[7], 5.0f, 310.0f);

    float aA = 3.5f * CAb, aB = 1.1f * CBb;
    float rden = rcp_f(aA + aB);
    float CAd = aA * rden, CBd = aB * rden;
    float Fr = __builtin_amdgcn_sqrtf(Hr);
    float Fb = __builtin_amdgcn_sqrtf(Hb);
    float rTr = rcp_f(Tr);
    float k1v = 20000.0f * __expf(-3000.0f * rTr);
    float r1 = k1v * CAr;
    float rHr = rcp_f(Hr), rHb = rcp_f(Hb);

    float dHr  = F + D - Fr;
    float dCAr = (F * (1.0f - CAr) + D * (CAd - CAr)) * rHr - r1;
    float dCBr = (D * (CBd - CBr) - F * CBr) * rHr + r1;
    float dTr  = (F * (320.0f - Tr) + D * (310.0f - Tr)) * rHr
               - (40.0f / 3.0f) * rHr + (2.0f / 3.0f) * r1;
    float dHb  = Fr - Fb - D;
    float dCAb = (Fr * (CAr - CAb) + D * (CAb - CAd)) * rHb;
    float dCBb = (Fr * (CBr - CBb) + D * (CBb - CBd)) * rHb;
    float dTb  = Fr * (Tr - Tb) * rHb + (40.0f / 3.0f) * rHb;

    kfg[0] = dHr  * (10.0f / 3.0f);
    kfg[1] = dCAr * 5.0f;
    kfg[2] = dCBr * 5.0f;
    kfg[3] = dTr  * 0.2f;
    kfg[4] = dHb  * (10.0f / 3.0f);
    kfg[5] = dCAb * 5.0f;
    kfg[6] = dCBb * 5.0f;
    kfg[7] = dTb  * 0.2f;
}

// h(C-layout, 4 tiles) -> poly-tanh -> f16 -> B-frags for next layer (K=64)
DEVI void transition(const f4_t acc[4], int iT0, int iT1, bool qlow,
                     H8& bf0, H8& bf1) {
    int pk[4][2];
#pragma unroll
    for (int mt = 0; mt < 4; ++mt) {
        f4_t th = tanh4(acc[mt]);
        pk[mt][0] = pkrtz_i(th[0], th[1]);
        pk[mt][1] = pkrtz_i(th[2], th[3]);
    }
#pragma unroll
    for (int kh = 0; kh < 2; ++kh) {
        H8& bf = kh ? bf1 : bf0;
#pragma unroll
        for (int j2 = 0; j2 < 4; ++j2) {
            int idx = (j2 >> 1) ? iT1 : iT0;
            int A = bperm(idx, pk[2 * kh + 0][j2 & 1]);
            int B = bperm(idx, pk[2 * kh + 1][j2 & 1]);
            bf.i[j2] = qlow ? A : B;
        }
    }
}

struct Weights {
    h8_t w1f[4][2], w2f[4][2], w3f[2];
    f4_t b1f[4], b2f[4], b3f;
};

// one RK slope: k = fg(x,u) + fnn([x, zvariant, u])
DEVI void eval_stage(const float x[8], const h2_t yv[16], const h2_t up[4],
                     int upair_i, float F, float D, const Weights& W,
                     int q, bool qlow, int iT0, int iT1, int iN0, int iN1,
                     float k[8]) {
    // ---- build B1 frags: in = [x(8), ypart(32), upseq(8), u(2), pad] ----
    H8 f0, f1;
#pragma unroll
    for (int i = 0; i < 4; ++i) {
        int pxi = pkrtz_i(x[2 * i], x[2 * i + 1]);
        f0.i[i] = qsel(q, pxi, h2i(yv[i]), h2i(yv[4 + i]), h2i(yv[8 + i]));
        f1.i[i] = qsel(q, h2i(yv[12 + i]), h2i(up[i]),
                       (i == 0) ? upair_i : 0, 0);
    }

    // ---- layer 1 ----
    f4_t a[4];
#pragma unroll
    for (int mt = 0; mt < 4; ++mt) {
        a[mt] = mfma16(W.w1f[mt][0], f0.v, W.b1f[mt]);
        a[mt] = mfma16(W.w1f[mt][1], f1.v, a[mt]);
    }
    H8 g0, g1;
    transition(a, iT0, iT1, qlow, g0, g1);

    // ---- layer 2 ----
#pragma unroll
    for (int mt = 0; mt < 4; ++mt) {
        a[mt] = mfma16(W.w2f[mt][0], g0.v, W.b2f[mt]);
        a[mt] = mfma16(W.w2f[mt][1], g1.v, a[mt]);
    }
    transition(a, iT0, iT1, qlow, g0, g1);

    // ---- layer 3 (8 outs, rows 8..15 zero-padded) ----
    f4_t a3 = mfma16(W.w3f[0], g0.v, W.b3f);
    a3 = mfma16(W.w3f[1], g1.v, a3);

    // gather nn[c] to every lane (batch = lane&15)
    float nn[8];
#pragma unroll
    for (int c = 0; c < 8; ++c) {
        int idx = (c < 4) ? iN0 : iN1;
        nn[c] = __int_as_float(bperm(idx, __float_as_int(a3[c & 3])));
    }

    float kfg[8];
    fg_eval(x, F, D, kfg);
#pragma unroll
    for (int c = 0; c < 8; ++c) k[c] = kfg[c] + nn[c];
}

__global__ __launch_bounds__(64, 1)
void cstr_mfma_kernel(const float* __restrict__ useq, const float* __restrict__ xGz0,
                      const float* __restrict__ W1, const float* __restrict__ b1,
                      const float* __restrict__ W2, const float* __restrict__ b2,
                      const float* __restrict__ W3, const float* __restrict__ b3,
                      float* __restrict__ out)
{
    const int lane = threadIdx.x & 63;
    const int m16 = lane & 15, q = lane >> 4;
    const bool qlow = (q < 2);
    const int b0 = blockIdx.x * 16;

    const int iT0 = (m16 + 16 * ((2 * q + 0) & 3)) << 2;
    const int iT1 = (m16 + 16 * ((2 * q + 1) & 3)) << 2;
    const int iN0 = m16 << 2;
    const int iN1 = (m16 + 16) << 2;

    // ---- preload weights as A-frags (f16) ----
    Weights W;
#pragma unroll
    for (int mt = 0; mt < 4; ++mt) {
#pragma unroll
        for (int kh = 0; kh < 2; ++kh) {
            H8 w1, w2;
#pragma unroll
            for (int j = 0; j < 8; ++j) {
                int k = 32 * kh + 8 * q + j;
                int n = 16 * mt + m16;
                _Float16 v1 = (k < 50) ? (_Float16)W1[k * 64 + n] : (_Float16)0.0f;
                _Float16 v2 = (_Float16)W2[k * 64 + n];
                ((_Float16*)&w1)[j] = v1;
                ((_Float16*)&w2)[j] = v2;
            }
            W.w1f[mt][kh] = w1.v;
            W.w2f[mt][kh] = w2.v;
        }
        f4_t bb1, bb2;
#pragma unroll
        for (int r = 0; r < 4; ++r) {
            bb1[r] = b1[16 * mt + 4 * q + r];
            bb2[r] = b2[16 * mt + 4 * q + r];
        }
        W.b1f[mt] = bb1;
        W.b2f[mt] = bb2;
    }
#pragma unroll
    for (int kh = 0; kh < 2; ++kh) {
        H8 w3;
#pragma unroll
        for (int j = 0; j < 8; ++j) {
            int k = 32 * kh + 8 * q + j;
            ((_Float16*)&w3)[j] = (m16 < 8) ? (_Float16)W3[k * 8 + m16] : (_Float16)0.0f;
        }
        W.w3f[kh] = w3.v;
    }
    {
        f4_t bb3;
#pragma unroll
        for (int r = 0; r < 4; ++r) {
            int c = 4 * q + r;
            bb3[r] = (c < 8) ? b3[c] : 0.0f;
        }
        W.b3f = bb3;
    }

    // ---- per-batch state (batch = lane&15, quad-replicated) ----
    const float* xz = xGz0 + (size_t)(b0 + m16) * 48;
    float xg[8];
#pragma unroll
    for (int c = 0; c < 8; ++c) xg[c] = xz[c];
    h2_t p[16];
#pragma unroll
    for (int i = 0; i < 16; ++i) p[i] = pkrtz(xz[8 + 2 * i], xz[9 + 2 * i]);
    h2_t up[4];
#pragma unroll
    for (int i = 0; i < 4; ++i) up[i] = pkrtz(xz[40 + 2 * i], xz[41 + 2 * i]);

    const float* ub = useq + (size_t)(b0 + m16) * 512;
    float* ob = out + (size_t)(b0 + m16) * 2048;

    float kc[8], ks[8], xv[8];

#pragma unroll 1
    for (int t = 0; t < 256; ++t) {
        const float2 uu = *(const float2*)(ub + 2 * t);
        const float u0 = uu.x, u1 = uu.y;
        const float F = fmaf(u0, 0.1f, 1.0f);
        const float D = fmaf(u1, 0.05f, 0.5f);
        const int upair_i = pkrtz_i(u0, u1);

        // ycat pairs = [ypseq(16 pairs), xG(4 pairs)]
        h2_t pc[20];
#pragma unroll
        for (int i = 0; i < 16; ++i) pc[i] = p[i];
#pragma unroll
        for (int i = 0; i < 4; ++i) pc[16 + i] = pkrtz(xg[2 * i], xg[2 * i + 1]);
        h2_t pi[16], ps[16];
        const h2_t half2c = { (_Float16)0.5f, (_Float16)0.5f };
#pragma unroll
        for (int i = 0; i < 16; ++i) {
            pi[i] = (pc[i] + pc[i + 4]) * half2c;
            ps[i] = pc[i + 4];
        }

        // ---- RK4 ----
        eval_stage(xg, p,  up, upair_i, F, D, W, q, qlow, iT0, iT1, iN0, iN1, kc);
#pragma unroll
        for (int c = 0; c < 8; ++c) { ks[c] = kc[c]; xv[c] = fmaf(0.005f, kc[c], xg[c]); }
        eval_stage(xv, pi, up, upair_i, F, D, W, q, qlow, iT0, iT1, iN0, iN1, kc);
#pragma unroll
        for (int c = 0; c < 8; ++c) { ks[c] = fmaf(2.0f, kc[c], ks[c]); xv[c] = fmaf(0.005f, kc[c], xg[c]); }
        eval_stage(xv, pi, up, upair_i, F, D, W, q, qlow, iT0, iT1, iN0, iN1, kc);
#pragma unroll
        for (int c = 0; c < 8; ++c) { ks[c] = fmaf(2.0f, kc[c], ks[c]); xv[c] = fmaf(0.01f, kc[c], xg[c]); }
        eval_stage(xv, ps, up, upair_i, F, D, W, q, qlow, iT0, iT1, iN0, iN1, kc);

        // ---- store y_t = xG (pre-update) ----
        {
            float s0 = (q == 0) ? xg[0] : (q == 1) ? xg[2] : (q == 2) ? xg[4] : xg[6];
            float s1 = (q == 0) ? xg[1] : (q == 1) ? xg[3] : (q == 2) ? xg[5] : xg[7];
            float2 st = { s0, s1 };
            *(float2*)(ob + t * 8 + 2 * q) = st;
        }

        // ---- state update ----
#pragma unroll
        for (int c = 0; c < 8; ++c) {
            ks[c] += kc[c];
            xg[c] = fmaf(0.0016666667f, ks[c], xg[c]);   // DELTA/6
        }
#pragma unroll
        for (int i = 0; i < 16; ++i) p[i] = ps[i];
        up[0] = up[1]; up[1] = up[2]; up[2] = up[3];
        { H2I u; u.i = upair_i; up[3] = u.h; }
    }
}

extern "C" void kernel_launch(void* const* d_in, const int* in_sizes, int n_in,
                              void* d_out, int out_size, void* d_ws, size_t ws_size,
                              hipStream_t stream) {
    const float* useq = (const float*)d_in[0];
    const float* xGz0 = (const float*)d_in[1];
    const float* W1   = (const float*)d_in[2];
    const float* b1   = (const float*)d_in[3];
    const float* W2   = (const float*)d_in[4];
    const float* b2   = (const float*)d_in[5];
    const float* W3   = (const float*)d_in[6];
    const float* b3   = (const float*)d_in[7];
    float* out = (float*)d_out;

    // 8192 batch / 16 per wave = 512 waves
    cstr_mfma_kernel<<<dim3(512), dim3(64), 0, stream>>>(
        useq, xGz0, W1, b1, W2, b2, W3, b3, out);
}